// Round 5
// baseline (623.939 us; speedup 1.0000x reference)
//
#include <hip/hip_runtime.h>

// GCN: 4x (gcn_conv + relu) + global mean pool + linear out.
// N=100000 nodes, E=1000000 edges, G=4096 graphs, F_IN=9, H=64.
// R5: (1) CSR build via bucketed counting sort (2048 buckets x ~49 nodes):
//       hist -> scans -> slice-local pair append -> per-bucket LDS sort with
//       coalesced csr dump; deg derived from bucket hist (k_deg removed).
//     (2) agg64/agg64_out split into two half-column passes (float2/lane,
//       per-column add order identical to R4) to halve the random-gather
//       line working set (25.6 -> 12.8 MB) and raise L2 hit rate.
//     (3) agg9 as wave=4 nodes x 16 lanes, register-broadcast indices,
//       bit-identical accumulation order to R2/R4's k_agg9.

static inline size_t align256(size_t x){ return (x + 255) & ~size_t(255); }

#define NBK 2048          // buckets
#define NSL 8             // edge slices (writer locality)

__global__ void k_zero(int* hist, float* gsum, int* gcount, int N, int G){
  int i = blockIdx.x*blockDim.x + threadIdx.x;
  if (i < NSL*NBK) hist[i] = 0;
  if (i < G){ gsum[i] = 0.f; gcount[i] = 0; }
}

__global__ void k_gcount(const int* __restrict__ batch, int* gcount, int N){
  int i = blockIdx.x*blockDim.x + threadIdx.x;
  if (i < N) atomicAdd(&gcount[batch[i]], 1);   // batch sorted -> wave-coalesced
}

// S1: per-(slice,bucket) edge histogram.  MUST use the same grid/mapping as
// k_pairscatter so each edge gets the same slice in both kernels.
__global__ void k_hist(const int* __restrict__ dst, int* hist, int E, int NPB){
  int slice = blockIdx.x & (NSL-1);
  for (int i = blockIdx.x*256 + threadIdx.x; i < E; i += gridDim.x*256){
    int b = dst[i] / NPB;
    atomicAdd(&hist[slice*NBK + b], 1);
  }
}

// per-bucket totals + exclusive slice prefixes within bucket
__global__ void k_hsum(const int* __restrict__ hist, int* sPre, int* tot){
  int b = blockIdx.x*256 + threadIdx.x;
  if (b < NBK){
    int r = 0;
    for (int s = 0; s < NSL; s++){ int c = hist[s*NBK + b]; sPre[s*NBK + b] = r; r += c; }
    tot[b] = r;
  }
}

// exclusive scan of 2048 bucket totals (1 block, 1024 threads, 2 elems each)
__global__ void k_scan2048(const int* __restrict__ tot, int* __restrict__ bbase){
  __shared__ int s[2048];
  int t = threadIdx.x;
  s[t] = tot[t]; s[t+1024] = tot[t+1024];
  __syncthreads();
  for (int off = 1; off < 2048; off <<= 1){
    int a  = (t      >= off) ? s[t-off]      : 0;
    int b2 = (t+1024 >= off) ? s[t+1024-off] : 0;
    __syncthreads();
    s[t] += a; s[t+1024] += b2;
    __syncthreads();
  }
  bbase[t]      = s[t]      - tot[t];
  bbase[t+1024] = s[t+1024] - tot[t+1024];
}

// per-(slice,bucket) region bases: bk (kept) and cw (mutable cursors)
__global__ void k_hbase(const int* __restrict__ bbase, const int* __restrict__ sPre,
                        int* bk, int* cw){
  int i = blockIdx.x*256 + threadIdx.x;
  if (i < NSL*NBK){
    int b = i & (NBK-1);
    int v = bbase[b] + sPre[i];
    bk[i] = v; cw[i] = v;
  }
}

// S3: append packed (dloc<<17 | src) into slice-local bucket regions
__global__ void k_pairscatter(const int* __restrict__ src, const int* __restrict__ dst,
                              int* cw, unsigned* __restrict__ pairs, int E, int NPB){
  int slice = blockIdx.x & (NSL-1);
  for (int i = blockIdx.x*256 + threadIdx.x; i < E; i += gridDim.x*256){
    int d = dst[i];
    int b = d / NPB;
    int dloc = d - b*NPB;
    int pos = atomicAdd(&cw[slice*NBK + b], 1);
    pairs[pos] = ((unsigned)dloc << 17) | (unsigned)src[i];
  }
}

// S4a: per-bucket local histogram -> deg[] (coalesced, no global atomics)
__global__ __launch_bounds__(256) void k_bdeg(
    const unsigned* __restrict__ pairs, const int* __restrict__ hist,
    const int* __restrict__ bk, int* __restrict__ deg, int N, int NPB){
  __shared__ int lh[64];
  __shared__ int sb[NSL], sc[NSL], so[NSL+1];
  int b = blockIdx.x, t = threadIdx.x;
  if (t < 64) lh[t] = 0;
  if (t < NSL){ sc[t] = hist[t*NBK + b]; sb[t] = bk[t*NBK + b]; }
  __syncthreads();
  if (t == 0){ int r = 0; for (int s = 0; s < NSL; s++){ so[s] = r; r += sc[s]; } so[NSL] = r; }
  __syncthreads();
  int tot = so[NSL];
  for (int i = t; i < tot; i += 256){
    int s = 0; while (i >= so[s+1]) s++;
    unsigned u = pairs[sb[s] + (i - so[s])];
    atomicAdd(&lh[u >> 17], 1);
  }
  __syncthreads();
  int n0 = b*NPB;
  if (t < NPB && n0 + t < N) deg[n0 + t] = lh[t];
}

__global__ void k_scanA(const int* __restrict__ deg, int* blockSums, int N){
  __shared__ int s[256];
  int t = threadIdx.x; int i = blockIdx.x*256 + t;
  s[t] = (i < N) ? deg[i] : 0;
  __syncthreads();
  for (int off=128; off>0; off>>=1){ if (t < off) s[t] += s[t+off]; __syncthreads(); }
  if (t==0) blockSums[blockIdx.x] = s[0];
}

// single-block exclusive scan of up to 512 block sums (NB=391 here)
__global__ void k_scanB(const int* __restrict__ blockSums, int* blockOffs, int NB){
  __shared__ int s[512];
  int t = threadIdx.x;
  int v = (t < NB) ? blockSums[t] : 0;
  s[t] = v; __syncthreads();
  for (int off=1; off<512; off<<=1){
    int add = (t>=off) ? s[t-off] : 0; __syncthreads();
    s[t] += add; __syncthreads();
  }
  if (t < NB) blockOffs[t] = s[t] - v;
}

__global__ void k_scanC(const int* __restrict__ deg, const int* __restrict__ blockOffs,
                        int* row_ptr, float* dis, int N){
  __shared__ int s[256];
  int t = threadIdx.x; int i = blockIdx.x*256 + t;
  int v = (i < N) ? deg[i] : 0;
  s[t] = v; __syncthreads();
  for (int off=1; off<256; off<<=1){
    int add = (t>=off) ? s[t-off] : 0; __syncthreads();
    s[t] += add; __syncthreads();
  }
  if (i < N){
    int row = blockOffs[blockIdx.x] + s[t] - v;   // exclusive
    row_ptr[i] = row;
    dis[i] = rsqrtf((float)(v + 1));              // +1 self-loop; deg>=1
    if (i == N-1) row_ptr[N] = blockOffs[blockIdx.x] + s[t];
  }
}

// S4b: per-bucket sort by local dst; coalesced csr dump.
__global__ __launch_bounds__(256) void k_place(
    const unsigned* __restrict__ pairs, const int* __restrict__ hist,
    const int* __restrict__ bk, const int* __restrict__ row_ptr,
    int* __restrict__ csr, int N, int NPB){
  __shared__ unsigned pr[2048];
  __shared__ int outA[2048];
  __shared__ int lh[64], ls[64], lc[64];
  __shared__ int sb[NSL], sc[NSL], so[NSL+1];
  int b = blockIdx.x, t = threadIdx.x;
  if (t < 64){ lh[t] = 0; lc[t] = 0; }
  if (t < NSL){ sc[t] = hist[t*NBK + b]; sb[t] = bk[t*NBK + b]; }
  __syncthreads();
  if (t == 0){ int r = 0; for (int s = 0; s < NSL; s++){ so[s] = r; r += sc[s]; } so[NSL] = r; }
  __syncthreads();
  int tot = so[NSL];
  int cap = tot < 2048 ? tot : 2048;
  // load (staged portion) + histogram over ALL pairs
  for (int i = t; i < tot; i += 256){
    int s = 0; while (i >= so[s+1]) s++;
    unsigned u = pairs[sb[s] + (i - so[s])];
    if (i < 2048) pr[i] = u;
    atomicAdd(&lh[u >> 17], 1);
  }
  __syncthreads();
  if (t == 0){ int r = 0; for (int d = 0; d < NPB; d++){ ls[d] = r; r += lh[d]; } }
  __syncthreads();
  int rp0 = row_ptr[b*NPB];
  // rank + place (staged into LDS when possible)
  for (int i = t; i < tot; i += 256){
    unsigned u;
    if (i < cap) u = pr[i];
    else { int s = 0; while (i >= so[s+1]) s++; u = pairs[sb[s] + (i - so[s])]; }
    int dloc = u >> 17;
    int r = atomicAdd(&lc[dloc], 1);
    int p = ls[dloc] + r;
    int srcv = (int)(u & 0x1FFFFu);
    if (p < 2048) outA[p] = srcv;
    else csr[rp0 + p] = srcv;
  }
  __syncthreads();
  for (int i = t; i < cap; i += 256) csr[rp0 + i] = outA[i];
}

// xs[n] = x[n] * dis[n]  (exact R2 numerics)
__global__ void k_premul(const float* __restrict__ x, const float* __restrict__ dis,
                         float* __restrict__ xs, int N){
  int i = blockIdx.x*blockDim.x + threadIdx.x;
  if (i < N*9) xs[i] = x[i]*dis[i/9];
}

// layer-1 aggregation: wave = 4 nodes x 16 lanes (f = lane&15, active f<9).
// Indices prefetched coalesced + shfl-broadcast; per-(n,f) accumulation
// sequence is IDENTICAL to R2/R4's k_agg9 (4 accumulators, stride-4 groups,
// sequential tail, combine ((a0+a1)+(a2+a3))*dn).
__global__ __launch_bounds__(256) void k_agg9w(
    const float* __restrict__ xs, const float* __restrict__ dis,
    const int* __restrict__ row_ptr, const int* __restrict__ csr,
    float* __restrict__ xagg, int N){
  int lane = threadIdx.x & 63;
  int wid = (blockIdx.x*blockDim.x + threadIdx.x) >> 6;
  int sub = lane >> 4, f = lane & 15;
  int n = wid*4 + sub;
  if (n >= N) return;
  float dn = dis[n];
  int s0 = row_ptr[n], deg = row_ptr[n+1] - s0;
  float a0 = (f < 9) ? xs[n*9 + f] : 0.f;       // self-loop term
  float a1 = 0.f, a2 = 0.f, a3 = 0.f;
  int base = 0;
  while (base < deg){
    int cnt = deg - base; if (cnt > 16) cnt = 16;
    int idxv = (f < cnt) ? csr[s0 + base + f] : 0;
    int j = 0;
    for (; j + 3 < cnt; j += 4){
      int e0 = __shfl(idxv, sub*16 + j,     64);
      int e1 = __shfl(idxv, sub*16 + j + 1, 64);
      int e2 = __shfl(idxv, sub*16 + j + 2, 64);
      int e3 = __shfl(idxv, sub*16 + j + 3, 64);
      if (f < 9){
        a0 += xs[e0*9 + f]; a1 += xs[e1*9 + f];
        a2 += xs[e2*9 + f]; a3 += xs[e3*9 + f];
      }
    }
    for (; j < cnt; j++){
      int e0 = __shfl(idxv, sub*16 + j, 64);
      if (f < 9) a0 += xs[e0*9 + f];
    }
    base += 16;
  }
  if (f < 9) xagg[n*9 + f] = ((a0+a1)+(a2+a3))*dn;
}

// h1 = relu(xagg @ W1 + b1)   (9 -> 64)
__global__ void k_lin1(const float* __restrict__ xagg, const float* __restrict__ W1,
                       const float* __restrict__ b1, float* __restrict__ h, int N){
  __shared__ float Wl[576];
  __shared__ float bl[64];
  int t = threadIdx.x;
  for (int i = t; i < 576; i += 256) Wl[i] = W1[i];
  if (t < 64) bl[t] = b1[t];
  __syncthreads();
  int tid = blockIdx.x*256 + t;
  int n = tid >> 6, f = tid & 63;
  if (n >= N) return;
  float acc = bl[f];
  #pragma unroll
  for (int k = 0; k < 9; k++) acc = fmaf(xagg[n*9+k], Wl[k*64+f], acc);
  h[tid] = fmaxf(acc, 0.f);
}

// m[n] = dis[n] * (h[n] @ W)   (64 -> 64); 16-node tiles, float4 outputs/thread
__global__ __launch_bounds__(256) void k_lin64(
    const float* __restrict__ h, const float* __restrict__ W,
    const float* __restrict__ dis, float* __restrict__ m, int N){
  __shared__ __align__(16) float Wl[64*64];
  __shared__ float hl[16*65];          // +1 pad: conflict-free broadcast reads
  int t = threadIdx.x;
  for (int i = t; i < 4096; i += 256) Wl[i] = W[i];
  int tiles = (N + 15) >> 4;
  int nl = t >> 4, q = t & 15;
  const float4* W4 = (const float4*)Wl;
  for (int tile = blockIdx.x; tile < tiles; tile += gridDim.x){
    int n0 = tile << 4;
    __syncthreads();
    #pragma unroll
    for (int j = 0; j < 4; j++){
      int idx = t + j*256;
      int node = n0 + (idx >> 6);
      float v = (node < N) ? h[n0*64 + idx] : 0.f;
      hl[(idx>>6)*65 + (idx&63)] = v;
    }
    __syncthreads();
    int node = n0 + nl;
    if (node < N){
      float4 acc = {0.f,0.f,0.f,0.f};
      #pragma unroll
      for (int k = 0; k < 64; k++){
        float hv = hl[nl*65 + k];
        float4 w = W4[k*16 + q];
        acc.x = fmaf(hv, w.x, acc.x);
        acc.y = fmaf(hv, w.y, acc.y);
        acc.z = fmaf(hv, w.z, acc.z);
        acc.w = fmaf(hv, w.w, acc.w);
      }
      float s = dis[node];
      float4 o = {acc.x*s, acc.y*s, acc.z*s, acc.w*s};
      *(float4*)&m[n0*64 + t*4] = o;
    }
  }
}

// h'[n] = relu(dis[n]*(m[n] + sum_nbr m[s]) + b) — HALF-COLUMN pass.
// colOff in {0,32}: lanes load float2 of cols [colOff+2q, +1]; per-column
// edge order identical to R4 (4 subs, stride 4, xor16/xor32 combine).
__global__ __launch_bounds__(256) void k_agg64(
    const float* __restrict__ m, const float* __restrict__ dis,
    const float* __restrict__ b,
    const int* __restrict__ row_ptr, const int* __restrict__ csr,
    float* __restrict__ h, int N, int colOff){
  int lane = threadIdx.x & 63;
  int n = (blockIdx.x*blockDim.x + threadIdx.x) >> 6;
  if (n >= N) return;
  int sub = lane >> 4, q = lane & 15;
  const float2* __restrict__ m2 = (const float2*)m;
  size_t cbase = (size_t)(colOff >> 1) + q;     // float2 index within row
  float2 self = m2[(size_t)n*32 + cbase];
  int s0 = row_ptr[n], deg = row_ptr[n+1] - s0;
  float ax = 0.f, ay = 0.f;
  int base = 0;
  while (base < deg){
    int cnt = deg - base; if (cnt > 64) cnt = 64;
    int idxv = (lane < cnt) ? csr[s0 + base + lane] : 0;
    #pragma unroll 2
    for (int e = sub; e < cnt; e += 4){
      int sA = __shfl(idxv, e, 64);
      float2 A = m2[(size_t)sA*32 + cbase];
      ax += A.x; ay += A.y;
    }
    base += 64;
  }
  ax += __shfl_xor(ax,16,64); ay += __shfl_xor(ay,16,64);
  ax += __shfl_xor(ax,32,64); ay += __shfl_xor(ay,32,64);
  float dn = dis[n];
  float2 bb = ((const float2*)b)[(colOff>>1) + q];
  float2 v;
  v.x = fmaxf(fmaf(ax + self.x, dn, bb.x), 0.f);
  v.y = fmaxf(fmaf(ay + self.y, dn, bb.y), 0.f);
  if (sub == 0) ((float2*)h)[(size_t)n*32 + cbase] = v;
}

// layer-4 half-column pass fused with output projection: partial dot over
// this pass's 32 columns, atomicAdd into gsum (2 atomics/node total).
__global__ __launch_bounds__(256) void k_agg64_out(
    const float* __restrict__ m, const float* __restrict__ dis,
    const float* __restrict__ b, const float* __restrict__ Wout,
    const int* __restrict__ batch,
    const int* __restrict__ row_ptr, const int* __restrict__ csr,
    float* gsum, int N, int colOff){
  int lane = threadIdx.x & 63;
  int n = (blockIdx.x*blockDim.x + threadIdx.x) >> 6;
  if (n >= N) return;
  int sub = lane >> 4, q = lane & 15;
  const float2* __restrict__ m2 = (const float2*)m;
  size_t cbase = (size_t)(colOff >> 1) + q;
  float2 self = m2[(size_t)n*32 + cbase];
  int s0 = row_ptr[n], deg = row_ptr[n+1] - s0;
  float ax = 0.f, ay = 0.f;
  int base = 0;
  while (base < deg){
    int cnt = deg - base; if (cnt > 64) cnt = 64;
    int idxv = (lane < cnt) ? csr[s0 + base + lane] : 0;
    #pragma unroll 2
    for (int e = sub; e < cnt; e += 4){
      int sA = __shfl(idxv, e, 64);
      float2 A = m2[(size_t)sA*32 + cbase];
      ax += A.x; ay += A.y;
    }
    base += 64;
  }
  ax += __shfl_xor(ax,16,64); ay += __shfl_xor(ay,16,64);
  ax += __shfl_xor(ax,32,64); ay += __shfl_xor(ay,32,64);
  float dn = dis[n];
  float2 bb = ((const float2*)b)[(colOff>>1) + q];
  float2 v;
  v.x = fmaxf(fmaf(ax + self.x, dn, bb.x), 0.f);
  v.y = fmaxf(fmaf(ay + self.y, dn, bb.y), 0.f);
  float2 wo = ((const float2*)Wout)[(colOff>>1) + q];
  float p = v.x*wo.x + v.y*wo.y;
  p += __shfl_xor(p,1,64); p += __shfl_xor(p,2,64);
  p += __shfl_xor(p,4,64); p += __shfl_xor(p,8,64);
  if (lane == 0) atomicAdd(&gsum[batch[n]], p);
}

__global__ void k_final(const float* __restrict__ gsum, const int* __restrict__ gcount,
                        const float* __restrict__ bout, float* __restrict__ out, int G){
  int g = blockIdx.x*blockDim.x + threadIdx.x;
  if (g < G){
    int c = gcount[g];
    out[g] = gsum[g]/(float)(c > 0 ? c : 1) + bout[0];
  }
}

extern "C" void kernel_launch(void* const* d_in, const int* in_sizes, int n_in,
                              void* d_out, int out_size, void* d_ws, size_t ws_size,
                              hipStream_t stream){
  const float* x    = (const float*)d_in[0];
  const int*   ei   = (const int*)d_in[1];
  const int*   batch= (const int*)d_in[2];
  const float* W1 = (const float*)d_in[3];  const float* b1 = (const float*)d_in[4];
  const float* W2 = (const float*)d_in[5];  const float* b2 = (const float*)d_in[6];
  const float* W3 = (const float*)d_in[7];  const float* b3 = (const float*)d_in[8];
  const float* W4 = (const float*)d_in[9];  const float* b4 = (const float*)d_in[10];
  const float* Wout = (const float*)d_in[11]; const float* bout = (const float*)d_in[12];
  float* out = (float*)d_out;

  const int N = in_sizes[0]/9;
  const int E = in_sizes[1]/2;
  const int G = out_size;
  const int* src = ei;        // edge_index[0]
  const int* dst = ei + E;    // edge_index[1]

  const int NPB = (N + NBK - 1) / NBK;       // nodes per bucket (49)
  const int NBused = (N + NPB - 1) / NPB;    // buckets actually used (2041)

  char* ws = (char*)d_ws;
  size_t off = 0;
  auto alloc = [&](size_t bytes){ void* p = ws + off; off = align256(off + bytes); return p; };
  int*      deg      = (int*)     alloc((size_t)N*4);
  int*      row_ptr  = (int*)     alloc((size_t)(N+1)*4);
  int*      csr      = (int*)     alloc((size_t)E*4);
  unsigned* pairs    = (unsigned*)alloc((size_t)E*4);
  float*    dis      = (float*)   alloc((size_t)N*4);
  const int NB = (N + 255)/256;   // 391 (< 512 required by k_scanB)
  int*      blockSums= (int*)     alloc((size_t)NB*4);
  int*      blockOffs= (int*)     alloc((size_t)NB*4);
  int*      hist     = (int*)     alloc((size_t)NSL*NBK*4);
  int*      sPre     = (int*)     alloc((size_t)NSL*NBK*4);
  int*      tot      = (int*)     alloc((size_t)NBK*4);
  int*      bbase    = (int*)     alloc((size_t)NBK*4);
  int*      bk       = (int*)     alloc((size_t)NSL*NBK*4);
  int*      cw       = (int*)     alloc((size_t)NSL*NBK*4);
  float*    gsum     = (float*)   alloc((size_t)G*4);
  int*      gcount   = (int*)     alloc((size_t)G*4);
  float*    bufA     = (float*)   alloc((size_t)N*64*4);
  float*    bufB     = (float*)   alloc((size_t)N*64*4);
  float*    xagg     = bufB;   // layer-1 9-feature aggregate aliases bufB
  float*    xs       = bufA;   // premultiplied x aliases bufA (freed by k_lin1 write)

  // ---- CSR build (bucketed counting sort) ----
  k_zero       <<<(N+255)/256, 256, 0, stream>>>(hist, gsum, gcount, N, G);
  k_gcount     <<<(N+255)/256, 256, 0, stream>>>(batch, gcount, N);
  k_hist       <<<2048, 256, 0, stream>>>(dst, hist, E, NPB);
  k_hsum       <<<(NBK+255)/256, 256, 0, stream>>>(hist, sPre, tot);
  k_scan2048   <<<1, 1024, 0, stream>>>(tot, bbase);
  k_hbase      <<<(NSL*NBK+255)/256, 256, 0, stream>>>(bbase, sPre, bk, cw);
  k_pairscatter<<<2048, 256, 0, stream>>>(src, dst, cw, pairs, E, NPB);
  k_bdeg       <<<NBused, 256, 0, stream>>>(pairs, hist, bk, deg, N, NPB);
  k_scanA      <<<NB, 256, 0, stream>>>(deg, blockSums, N);
  k_scanB      <<<1, 512, 0, stream>>>(blockSums, blockOffs, NB);
  k_scanC      <<<NB, 256, 0, stream>>>(deg, blockOffs, row_ptr, dis, N);
  k_place      <<<NBused, 256, 0, stream>>>(pairs, hist, bk, row_ptr, csr, N, NPB);

  // ---- layer 1: premultiply, aggregate (9 feats), transform ----
  k_premul<<<(N*9+255)/256, 256, 0, stream>>>(x, dis, xs, N);
  k_agg9w <<<(N/4*64+255)/256, 256, 0, stream>>>(xs, dis, row_ptr, csr, xagg, N);
  k_lin1  <<<(N*64+255)/256, 256, 0, stream>>>(xagg, W1, b1, bufA, N);

  // ---- layers 2-3: transform then aggregate (two half-column passes) ----
  const float* Ws[2] = {W2, W3};
  const float* bs[2] = {b2, b3};
  for (int l = 0; l < 2; l++){
    k_lin64<<<1792, 256, 0, stream>>>(bufA, Ws[l], dis, bufB, N);
    k_agg64<<<(N*64+255)/256, 256, 0, stream>>>(bufB, dis, bs[l], row_ptr, csr, bufA, N, 0);
    k_agg64<<<(N*64+255)/256, 256, 0, stream>>>(bufB, dis, bs[l], row_ptr, csr, bufA, N, 32);
  }

  // ---- layer 4: transform, then fused aggregate+project+pool (two passes) ----
  k_lin64<<<1792, 256, 0, stream>>>(bufA, W4, dis, bufB, N);
  k_agg64_out<<<(N*64+255)/256, 256, 0, stream>>>(bufB, dis, b4, Wout, batch,
                                                  row_ptr, csr, gsum, N, 0);
  k_agg64_out<<<(N*64+255)/256, 256, 0, stream>>>(bufB, dis, b4, Wout, batch,
                                                  row_ptr, csr, gsum, N, 32);

  k_final<<<(G+255)/256, 256, 0, stream>>>(gsum, gcount, bout, out, G);
}

// Round 6
// 492.779 us; speedup vs baseline: 1.2662x; 1.2662x over previous
//
#include <hip/hip_runtime.h>

// GCN: 4x (gcn_conv + relu) + global mean pool + linear out.
// N=100000 nodes, E=1000000 edges, G=4096 graphs, F_IN=9, H=64.
// R6: half-column split REVERTED (R5 showed per-pass time tracks instruction/
//     latency structure, not bytes).  Keep R5's bucketed counting-sort CSR
//     build.  A/B: layer-2 agg uses persistent-wave pipelined k_agg64p
//     (prefetch next node's row_ptr/csr/self during current gather); layers
//     3/4 use the known-good R4 full-row kernels.  k_hsum/scan2048/hbase
//     merged into k_meta; premul folded into scanC.

static inline size_t align256(size_t x){ return (x + 255) & ~size_t(255); }

#define NBK 2048          // buckets
#define NSL 8             // edge slices (writer locality)

__global__ void k_zero(int* hist, float* gsum, int* gcount, int N, int G){
  int i = blockIdx.x*blockDim.x + threadIdx.x;
  if (i < NSL*NBK) hist[i] = 0;
  if (i < G){ gsum[i] = 0.f; gcount[i] = 0; }
}

__global__ void k_gcount(const int* __restrict__ batch, int* gcount, int N){
  int i = blockIdx.x*blockDim.x + threadIdx.x;
  if (i < N) atomicAdd(&gcount[batch[i]], 1);   // batch sorted -> wave-coalesced
}

// S1: per-(slice,bucket) edge histogram.  Same grid/mapping as k_pairscatter.
__global__ void k_hist(const int* __restrict__ dst, int* hist, int E, int NPB){
  int slice = blockIdx.x & (NSL-1);
  for (int i = blockIdx.x*256 + threadIdx.x; i < E; i += gridDim.x*256){
    int b = dst[i] / NPB;
    atomicAdd(&hist[slice*NBK + b], 1);
  }
}

// S2 merged: bucket totals -> exclusive scan -> per-(slice,bucket) bases
__global__ void k_meta(const int* __restrict__ hist, int* bk, int* cw){
  __shared__ int s[2048];
  int t = threadIdx.x;                 // 1024 threads, each owns buckets t, t+1024
  int tot0 = 0, tot1 = 0;
  for (int sl = 0; sl < NSL; sl++){ tot0 += hist[sl*NBK + t]; tot1 += hist[sl*NBK + t + 1024]; }
  s[t] = tot0; s[t+1024] = tot1;
  __syncthreads();
  for (int off = 1; off < 2048; off <<= 1){
    int a  = (t      >= off) ? s[t-off]      : 0;
    int b2 = (t+1024 >= off) ? s[t+1024-off] : 0;
    __syncthreads();
    s[t] += a; s[t+1024] += b2;
    __syncthreads();
  }
  int r0 = s[t] - tot0, r1 = s[t+1024] - tot1;   // exclusive bucket bases
  for (int sl = 0; sl < NSL; sl++){
    int c0 = hist[sl*NBK + t], c1 = hist[sl*NBK + t + 1024];
    bk[sl*NBK + t]        = r0; cw[sl*NBK + t]        = r0; r0 += c0;
    bk[sl*NBK + t + 1024] = r1; cw[sl*NBK + t + 1024] = r1; r1 += c1;
  }
}

// S3: append packed (dloc<<17 | src) into slice-local bucket regions
__global__ void k_pairscatter(const int* __restrict__ src, const int* __restrict__ dst,
                              int* cw, unsigned* __restrict__ pairs, int E, int NPB){
  int slice = blockIdx.x & (NSL-1);
  for (int i = blockIdx.x*256 + threadIdx.x; i < E; i += gridDim.x*256){
    int d = dst[i];
    int b = d / NPB;
    int dloc = d - b*NPB;
    int pos = atomicAdd(&cw[slice*NBK + b], 1);
    pairs[pos] = ((unsigned)dloc << 17) | (unsigned)src[i];
  }
}

// S4a: per-bucket local histogram -> deg[]
__global__ __launch_bounds__(256) void k_bdeg(
    const unsigned* __restrict__ pairs, const int* __restrict__ hist,
    const int* __restrict__ bk, int* __restrict__ deg, int N, int NPB){
  __shared__ int lh[64];
  __shared__ int sb[NSL], sc[NSL], so[NSL+1];
  int b = blockIdx.x, t = threadIdx.x;
  if (t < 64) lh[t] = 0;
  if (t < NSL){ sc[t] = hist[t*NBK + b]; sb[t] = bk[t*NBK + b]; }
  __syncthreads();
  if (t == 0){ int r = 0; for (int s = 0; s < NSL; s++){ so[s] = r; r += sc[s]; } so[NSL] = r; }
  __syncthreads();
  int tot = so[NSL];
  for (int i = t; i < tot; i += 256){
    int s = 0; while (i >= so[s+1]) s++;
    unsigned u = pairs[sb[s] + (i - so[s])];
    atomicAdd(&lh[u >> 17], 1);
  }
  __syncthreads();
  int n0 = b*NPB;
  if (t < NPB && n0 + t < N) deg[n0 + t] = lh[t];
}

__global__ void k_scanA(const int* __restrict__ deg, int* blockSums, int N){
  __shared__ int s[256];
  int t = threadIdx.x; int i = blockIdx.x*256 + t;
  s[t] = (i < N) ? deg[i] : 0;
  __syncthreads();
  for (int off=128; off>0; off>>=1){ if (t < off) s[t] += s[t+off]; __syncthreads(); }
  if (t==0) blockSums[blockIdx.x] = s[0];
}

// single-block exclusive scan of up to 512 block sums (NB=391 here)
__global__ void k_scanB(const int* __restrict__ blockSums, int* blockOffs, int NB){
  __shared__ int s[512];
  int t = threadIdx.x;
  int v = (t < NB) ? blockSums[t] : 0;
  s[t] = v; __syncthreads();
  for (int off=1; off<512; off<<=1){
    int add = (t>=off) ? s[t-off] : 0; __syncthreads();
    s[t] += add; __syncthreads();
  }
  if (t < NB) blockOffs[t] = s[t] - v;
}

// scan finish + dis + xs premultiply (xs[i*9+k] = x[i*9+k]*dis[i], exact R2 numerics)
__global__ void k_scanC(const int* __restrict__ deg, const int* __restrict__ blockOffs,
                        const float* __restrict__ x,
                        int* row_ptr, float* dis, float* __restrict__ xs, int N){
  __shared__ int s[256];
  int t = threadIdx.x; int i = blockIdx.x*256 + t;
  int v = (i < N) ? deg[i] : 0;
  s[t] = v; __syncthreads();
  for (int off=1; off<256; off<<=1){
    int add = (t>=off) ? s[t-off] : 0; __syncthreads();
    s[t] += add; __syncthreads();
  }
  if (i < N){
    int row = blockOffs[blockIdx.x] + s[t] - v;   // exclusive
    row_ptr[i] = row;
    float d = rsqrtf((float)(v + 1));             // +1 self-loop; deg>=1
    dis[i] = d;
    if (i == N-1) row_ptr[N] = blockOffs[blockIdx.x] + s[t];
    #pragma unroll
    for (int k = 0; k < 9; k++) xs[i*9+k] = x[i*9+k]*d;
  }
}

// S4b: per-bucket sort by local dst; coalesced csr dump.
__global__ __launch_bounds__(256) void k_place(
    const unsigned* __restrict__ pairs, const int* __restrict__ hist,
    const int* __restrict__ bk, const int* __restrict__ row_ptr,
    int* __restrict__ csr, int N, int NPB){
  __shared__ unsigned pr[2048];
  __shared__ int outA[2048];
  __shared__ int lh[64], ls[64], lc[64];
  __shared__ int sb[NSL], sc[NSL], so[NSL+1];
  int b = blockIdx.x, t = threadIdx.x;
  if (t < 64){ lh[t] = 0; lc[t] = 0; }
  if (t < NSL){ sc[t] = hist[t*NBK + b]; sb[t] = bk[t*NBK + b]; }
  __syncthreads();
  if (t == 0){ int r = 0; for (int s = 0; s < NSL; s++){ so[s] = r; r += sc[s]; } so[NSL] = r; }
  __syncthreads();
  int tot = so[NSL];
  int cap = tot < 2048 ? tot : 2048;
  for (int i = t; i < tot; i += 256){
    int s = 0; while (i >= so[s+1]) s++;
    unsigned u = pairs[sb[s] + (i - so[s])];
    if (i < 2048) pr[i] = u;
    atomicAdd(&lh[u >> 17], 1);
  }
  __syncthreads();
  if (t == 0){ int r = 0; for (int d = 0; d < NPB; d++){ ls[d] = r; r += lh[d]; } }
  __syncthreads();
  int rp0 = row_ptr[b*NPB];
  for (int i = t; i < tot; i += 256){
    unsigned u;
    if (i < cap) u = pr[i];
    else { int s = 0; while (i >= so[s+1]) s++; u = pairs[sb[s] + (i - so[s])]; }
    int dloc = u >> 17;
    int r = atomicAdd(&lc[dloc], 1);
    int p = ls[dloc] + r;
    int srcv = (int)(u & 0x1FFFFu);
    if (p < 2048) outA[p] = srcv;
    else csr[rp0 + p] = srcv;
  }
  __syncthreads();
  for (int i = t; i < cap; i += 256) csr[rp0 + i] = outA[i];
}

// layer-1 aggregation: wave = 4 nodes x 16 lanes (f = lane&15, active f<9).
__global__ __launch_bounds__(256) void k_agg9w(
    const float* __restrict__ xs, const float* __restrict__ dis,
    const int* __restrict__ row_ptr, const int* __restrict__ csr,
    float* __restrict__ xagg, int N){
  int lane = threadIdx.x & 63;
  int wid = (blockIdx.x*blockDim.x + threadIdx.x) >> 6;
  int sub = lane >> 4, f = lane & 15;
  int n = wid*4 + sub;
  if (n >= N) return;
  float dn = dis[n];
  int s0 = row_ptr[n], deg = row_ptr[n+1] - s0;
  float a0 = (f < 9) ? xs[n*9 + f] : 0.f;       // self-loop term
  float a1 = 0.f, a2 = 0.f, a3 = 0.f;
  int base = 0;
  while (base < deg){
    int cnt = deg - base; if (cnt > 16) cnt = 16;
    int idxv = (f < cnt) ? csr[s0 + base + f] : 0;
    int j = 0;
    for (; j + 3 < cnt; j += 4){
      int e0 = __shfl(idxv, sub*16 + j,     64);
      int e1 = __shfl(idxv, sub*16 + j + 1, 64);
      int e2 = __shfl(idxv, sub*16 + j + 2, 64);
      int e3 = __shfl(idxv, sub*16 + j + 3, 64);
      if (f < 9){
        a0 += xs[e0*9 + f]; a1 += xs[e1*9 + f];
        a2 += xs[e2*9 + f]; a3 += xs[e3*9 + f];
      }
    }
    for (; j < cnt; j++){
      int e0 = __shfl(idxv, sub*16 + j, 64);
      if (f < 9) a0 += xs[e0*9 + f];
    }
    base += 16;
  }
  if (f < 9) xagg[n*9 + f] = ((a0+a1)+(a2+a3))*dn;
}

// h1 = relu(xagg @ W1 + b1)   (9 -> 64)
__global__ void k_lin1(const float* __restrict__ xagg, const float* __restrict__ W1,
                       const float* __restrict__ b1, float* __restrict__ h, int N){
  __shared__ float Wl[576];
  __shared__ float bl[64];
  int t = threadIdx.x;
  for (int i = t; i < 576; i += 256) Wl[i] = W1[i];
  if (t < 64) bl[t] = b1[t];
  __syncthreads();
  int tid = blockIdx.x*256 + t;
  int n = tid >> 6, f = tid & 63;
  if (n >= N) return;
  float acc = bl[f];
  #pragma unroll
  for (int k = 0; k < 9; k++) acc = fmaf(xagg[n*9+k], Wl[k*64+f], acc);
  h[tid] = fmaxf(acc, 0.f);
}

// m[n] = dis[n] * (h[n] @ W)   (64 -> 64); 16-node tiles, float4 outputs/thread
__global__ __launch_bounds__(256) void k_lin64(
    const float* __restrict__ h, const float* __restrict__ W,
    const float* __restrict__ dis, float* __restrict__ m, int N){
  __shared__ __align__(16) float Wl[64*64];
  __shared__ float hl[16*65];
  int t = threadIdx.x;
  for (int i = t; i < 4096; i += 256) Wl[i] = W[i];
  int tiles = (N + 15) >> 4;
  int nl = t >> 4, q = t & 15;
  const float4* W4 = (const float4*)Wl;
  for (int tile = blockIdx.x; tile < tiles; tile += gridDim.x){
    int n0 = tile << 4;
    __syncthreads();
    #pragma unroll
    for (int j = 0; j < 4; j++){
      int idx = t + j*256;
      int node = n0 + (idx >> 6);
      float v = (node < N) ? h[n0*64 + idx] : 0.f;
      hl[(idx>>6)*65 + (idx&63)] = v;
    }
    __syncthreads();
    int node = n0 + nl;
    if (node < N){
      float4 acc = {0.f,0.f,0.f,0.f};
      #pragma unroll
      for (int k = 0; k < 64; k++){
        float hv = hl[nl*65 + k];
        float4 w = W4[k*16 + q];
        acc.x = fmaf(hv, w.x, acc.x);
        acc.y = fmaf(hv, w.y, acc.y);
        acc.z = fmaf(hv, w.z, acc.z);
        acc.w = fmaf(hv, w.w, acc.w);
      }
      float s = dis[node];
      float4 o = {acc.x*s, acc.y*s, acc.z*s, acc.w*s};
      *(float4*)&m[n0*64 + t*4] = o;
    }
  }
}

// R4 full-row aggregate: wave = 1 node, 4 subgroups x 16 lanes, float4/lane.
__global__ __launch_bounds__(256) void k_agg64(
    const float* __restrict__ m, const float* __restrict__ dis,
    const float* __restrict__ b,
    const int* __restrict__ row_ptr, const int* __restrict__ csr,
    float* __restrict__ h, int N){
  int lane = threadIdx.x & 63;
  int n = (blockIdx.x*blockDim.x + threadIdx.x) >> 6;
  if (n >= N) return;
  int sub = lane >> 4, q = lane & 15;
  const float4* __restrict__ m4 = (const float4*)m;
  float4 self = m4[(size_t)n*16 + q];
  int s0 = row_ptr[n], deg = row_ptr[n+1] - s0;
  float ax=0.f, ay=0.f, az=0.f, aw=0.f;
  int base = 0;
  while (base < deg){
    int cnt = deg - base; if (cnt > 64) cnt = 64;
    int idxv = (lane < cnt) ? csr[s0 + base + lane] : 0;
    #pragma unroll 2
    for (int e = sub; e < cnt; e += 4){
      int sA = __shfl(idxv, e, 64);
      float4 A = m4[(size_t)sA*16 + q];
      ax += A.x; ay += A.y; az += A.z; aw += A.w;
    }
    base += 64;
  }
  ax += __shfl_xor(ax,16,64); ay += __shfl_xor(ay,16,64);
  az += __shfl_xor(az,16,64); aw += __shfl_xor(aw,16,64);
  ax += __shfl_xor(ax,32,64); ay += __shfl_xor(ay,32,64);
  az += __shfl_xor(az,32,64); aw += __shfl_xor(aw,32,64);
  float dn = dis[n];
  const float4* b4 = (const float4*)b;
  float4 bb = b4[q];
  float4 v;
  v.x = fmaxf(fmaf(ax + self.x, dn, bb.x), 0.f);
  v.y = fmaxf(fmaf(ay + self.y, dn, bb.y), 0.f);
  v.z = fmaxf(fmaf(az + self.z, dn, bb.z), 0.f);
  v.w = fmaxf(fmaf(aw + self.w, dn, bb.w), 0.f);
  if (sub == 0) ((float4*)h)[(size_t)n*16 + q] = v;
}

// A/B EXPERIMENT (layer 2): persistent waves, grid-stride over nodes, with
// next-node row_ptr/csr/self prefetch issued before the current gather wait.
// Per-node gather order identical to k_agg64 (bit-compatible result).
__global__ __launch_bounds__(256) void k_agg64p(
    const float* __restrict__ m, const float* __restrict__ dis,
    const float* __restrict__ b,
    const int* __restrict__ row_ptr, const int* __restrict__ csr,
    float* __restrict__ h, int N, int nwaves){
  int lane = threadIdx.x & 63;
  int wv = (blockIdx.x*blockDim.x + threadIdx.x) >> 6;
  int sub = lane >> 4, q = lane & 15;
  const float4* __restrict__ m4 = (const float4*)m;
  const float4* b4 = (const float4*)b;
  float4 bb = b4[q];
  int n = wv;
  if (n >= N) return;
  // stage-0 prefetch for the first node
  int s0 = row_ptr[n];
  int deg = row_ptr[n+1] - s0;
  int pf = (lane < deg) ? csr[s0 + lane] : 0;
  float4 self = m4[(size_t)n*16 + q];
  while (true){
    int curN = n, curS0 = s0, curDeg = deg, idxv = pf;
    float4 curSelf = self;
    // prefetch the NEXT node while current gathers are outstanding
    n += nwaves;
    bool more = (n < N);
    if (more){
      s0 = row_ptr[n];
      deg = row_ptr[n+1] - s0;
      pf = (lane < deg) ? csr[s0 + lane] : 0;
      self = m4[(size_t)n*16 + q];
    }
    float ax=0.f, ay=0.f, az=0.f, aw=0.f;
    int cnt0 = curDeg < 64 ? curDeg : 64;
    #pragma unroll 2
    for (int e = sub; e < cnt0; e += 4){
      int sA = __shfl(idxv, e, 64);
      float4 A = m4[(size_t)sA*16 + q];
      ax += A.x; ay += A.y; az += A.z; aw += A.w;
    }
    int base = 64;                      // rare tail (deg > 64)
    while (base < curDeg){
      int cnt = curDeg - base; if (cnt > 64) cnt = 64;
      int iv2 = (lane < cnt) ? csr[curS0 + base + lane] : 0;
      #pragma unroll 2
      for (int e = sub; e < cnt; e += 4){
        int sA = __shfl(iv2, e, 64);
        float4 A = m4[(size_t)sA*16 + q];
        ax += A.x; ay += A.y; az += A.z; aw += A.w;
      }
      base += 64;
    }
    ax += __shfl_xor(ax,16,64); ay += __shfl_xor(ay,16,64);
    az += __shfl_xor(az,16,64); aw += __shfl_xor(aw,16,64);
    ax += __shfl_xor(ax,32,64); ay += __shfl_xor(ay,32,64);
    az += __shfl_xor(az,32,64); aw += __shfl_xor(aw,32,64);
    float dn = dis[curN];
    float4 v;
    v.x = fmaxf(fmaf(ax + curSelf.x, dn, bb.x), 0.f);
    v.y = fmaxf(fmaf(ay + curSelf.y, dn, bb.y), 0.f);
    v.z = fmaxf(fmaf(az + curSelf.z, dn, bb.z), 0.f);
    v.w = fmaxf(fmaf(aw + curSelf.w, dn, bb.w), 0.f);
    if (sub == 0) ((float4*)h)[(size_t)curN*16 + q] = v;
    if (!more) break;
  }
}

// layer-4 aggregation fused with output projection + graph-sum atomic (R4).
__global__ __launch_bounds__(256) void k_agg64_out(
    const float* __restrict__ m, const float* __restrict__ dis,
    const float* __restrict__ b, const float* __restrict__ Wout,
    const int* __restrict__ batch,
    const int* __restrict__ row_ptr, const int* __restrict__ csr,
    float* gsum, int N){
  int lane = threadIdx.x & 63;
  int n = (blockIdx.x*blockDim.x + threadIdx.x) >> 6;
  if (n >= N) return;
  int sub = lane >> 4, q = lane & 15;
  const float4* __restrict__ m4 = (const float4*)m;
  float4 self = m4[(size_t)n*16 + q];
  int s0 = row_ptr[n], deg = row_ptr[n+1] - s0;
  float ax=0.f, ay=0.f, az=0.f, aw=0.f;
  int base = 0;
  while (base < deg){
    int cnt = deg - base; if (cnt > 64) cnt = 64;
    int idxv = (lane < cnt) ? csr[s0 + base + lane] : 0;
    #pragma unroll 2
    for (int e = sub; e < cnt; e += 4){
      int sA = __shfl(idxv, e, 64);
      float4 A = m4[(size_t)sA*16 + q];
      ax += A.x; ay += A.y; az += A.z; aw += A.w;
    }
    base += 64;
  }
  ax += __shfl_xor(ax,16,64); ay += __shfl_xor(ay,16,64);
  az += __shfl_xor(az,16,64); aw += __shfl_xor(aw,16,64);
  ax += __shfl_xor(ax,32,64); ay += __shfl_xor(ay,32,64);
  az += __shfl_xor(az,32,64); aw += __shfl_xor(aw,32,64);
  float dn = dis[n];
  const float4* b4 = (const float4*)b;
  float4 bb = b4[q];
  float4 v;
  v.x = fmaxf(fmaf(ax + self.x, dn, bb.x), 0.f);
  v.y = fmaxf(fmaf(ay + self.y, dn, bb.y), 0.f);
  v.z = fmaxf(fmaf(az + self.z, dn, bb.z), 0.f);
  v.w = fmaxf(fmaf(aw + self.w, dn, bb.w), 0.f);
  const float4* Wo4 = (const float4*)Wout;
  float4 wo = Wo4[q];
  float p = v.x*wo.x + v.y*wo.y + v.z*wo.z + v.w*wo.w;
  p += __shfl_xor(p,1,64); p += __shfl_xor(p,2,64);
  p += __shfl_xor(p,4,64); p += __shfl_xor(p,8,64);
  if (lane == 0) atomicAdd(&gsum[batch[n]], p);
}

__global__ void k_final(const float* __restrict__ gsum, const int* __restrict__ gcount,
                        const float* __restrict__ bout, float* __restrict__ out, int G){
  int g = blockIdx.x*blockDim.x + threadIdx.x;
  if (g < G){
    int c = gcount[g];
    out[g] = gsum[g]/(float)(c > 0 ? c : 1) + bout[0];
  }
}

extern "C" void kernel_launch(void* const* d_in, const int* in_sizes, int n_in,
                              void* d_out, int out_size, void* d_ws, size_t ws_size,
                              hipStream_t stream){
  const float* x    = (const float*)d_in[0];
  const int*   ei   = (const int*)d_in[1];
  const int*   batch= (const int*)d_in[2];
  const float* W1 = (const float*)d_in[3];  const float* b1 = (const float*)d_in[4];
  const float* W2 = (const float*)d_in[5];  const float* b2 = (const float*)d_in[6];
  const float* W3 = (const float*)d_in[7];  const float* b3 = (const float*)d_in[8];
  const float* W4 = (const float*)d_in[9];  const float* b4 = (const float*)d_in[10];
  const float* Wout = (const float*)d_in[11]; const float* bout = (const float*)d_in[12];
  float* out = (float*)d_out;

  const int N = in_sizes[0]/9;
  const int E = in_sizes[1]/2;
  const int G = out_size;
  const int* src = ei;        // edge_index[0]
  const int* dst = ei + E;    // edge_index[1]

  const int NPB = (N + NBK - 1) / NBK;       // nodes per bucket (49)
  const int NBused = (N + NPB - 1) / NPB;    // buckets actually used (2041)

  char* ws = (char*)d_ws;
  size_t off = 0;
  auto alloc = [&](size_t bytes){ void* p = ws + off; off = align256(off + bytes); return p; };
  int*      deg      = (int*)     alloc((size_t)N*4);
  int*      row_ptr  = (int*)     alloc((size_t)(N+1)*4);
  int*      csr      = (int*)     alloc((size_t)E*4);
  unsigned* pairs    = (unsigned*)alloc((size_t)E*4);
  float*    dis      = (float*)   alloc((size_t)N*4);
  float*    xs       = (float*)   alloc((size_t)N*9*4);
  const int NB = (N + 255)/256;   // 391 (< 512 required by k_scanB)
  int*      blockSums= (int*)     alloc((size_t)NB*4);
  int*      blockOffs= (int*)     alloc((size_t)NB*4);
  int*      hist     = (int*)     alloc((size_t)NSL*NBK*4);
  int*      bk       = (int*)     alloc((size_t)NSL*NBK*4);
  int*      cw       = (int*)     alloc((size_t)NSL*NBK*4);
  float*    gsum     = (float*)   alloc((size_t)G*4);
  int*      gcount   = (int*)     alloc((size_t)G*4);
  float*    bufA     = (float*)   alloc((size_t)N*64*4);
  float*    bufB     = (float*)   alloc((size_t)N*64*4);
  float*    xagg     = bufB;   // layer-1 9-feature aggregate aliases bufB

  // ---- CSR build (bucketed counting sort) ----
  k_zero       <<<(N+255)/256, 256, 0, stream>>>(hist, gsum, gcount, N, G);
  k_gcount     <<<(N+255)/256, 256, 0, stream>>>(batch, gcount, N);
  k_hist       <<<2048, 256, 0, stream>>>(dst, hist, E, NPB);
  k_meta       <<<1, 1024, 0, stream>>>(hist, bk, cw);
  k_pairscatter<<<2048, 256, 0, stream>>>(src, dst, cw, pairs, E, NPB);
  k_bdeg       <<<NBused, 256, 0, stream>>>(pairs, hist, bk, deg, N, NPB);
  k_scanA      <<<NB, 256, 0, stream>>>(deg, blockSums, N);
  k_scanB      <<<1, 512, 0, stream>>>(blockSums, blockOffs, NB);
  k_scanC      <<<NB, 256, 0, stream>>>(deg, blockOffs, x, row_ptr, dis, xs, N);
  k_place      <<<NBused, 256, 0, stream>>>(pairs, hist, bk, row_ptr, csr, N, NPB);

  // ---- layer 1: aggregate (9 feats) then transform ----
  k_agg9w <<<(N/4*64+255)/256, 256, 0, stream>>>(xs, dis, row_ptr, csr, xagg, N);
  k_lin1  <<<(N*64+255)/256, 256, 0, stream>>>(xagg, W1, b1, bufA, N);

  // ---- layer 2: transform + PIPELINED persistent aggregate (A/B arm) ----
  k_lin64 <<<1792, 256, 0, stream>>>(bufA, W2, dis, bufB, N);
  {
    const int blocks = 1024;                 // 4096 persistent waves
    k_agg64p<<<blocks, 256, 0, stream>>>(bufB, dis, b2, row_ptr, csr, bufA, N, blocks*4);
  }

  // ---- layer 3: transform + R4 aggregate (control arm) ----
  k_lin64 <<<1792, 256, 0, stream>>>(bufA, W3, dis, bufB, N);
  k_agg64 <<<(N*64+255)/256, 256, 0, stream>>>(bufB, dis, b3, row_ptr, csr, bufA, N);

  // ---- layer 4: transform + fused aggregate/project/pool ----
  k_lin64 <<<1792, 256, 0, stream>>>(bufA, W4, dis, bufB, N);
  k_agg64_out<<<(N*64+255)/256, 256, 0, stream>>>(bufB, dis, b4, Wout, batch,
                                                  row_ptr, csr, gsum, N);

  k_final<<<(G+255)/256, 256, 0, stream>>>(gsum, gcount, bout, out, G);
}